// Round 10
// baseline (129.535 us; speedup 1.0000x reference)
//
#include <hip/hip_runtime.h>
#include <stdint.h>

#define Hs 96
#define Ws 96
#define HW 9216

typedef _Float16 h2 __attribute__((ext_vector_type(2)));
typedef _Float16 f16x8 __attribute__((ext_vector_type(8)));
typedef float f32x4 __attribute__((ext_vector_type(4)));

// nested-fma bilinear: 1 pk_mul + 3 pk_fma (FP contraction)
__device__ __forceinline__ unsigned interp4(h2 w00, h2 w01, h2 w10, h2 w11,
                                            unsigned a, unsigned bq, unsigned c,
                                            unsigned d) {
  h2 r = w10 * __builtin_bit_cast(h2, c) + w11 * __builtin_bit_cast(h2, d);
  r = w01 * __builtin_bit_cast(h2, bq) + r;
  r = w00 * __builtin_bit_cast(h2, a) + r;
  return __builtin_bit_cast(unsigned, r);
}

// ---- kernel 1: fused prep ----
// blk < 2304: NCHW fp32 -> NHWC fp16 transpose (32x-tile per block)
// blk >= 2304: weight fp32 [O][C][9] -> fp16 planes Wg[t*8+c8][o][8ch]
__global__ __launch_bounds__(256) void k_prep(const float* __restrict__ in,
                                              _Float16* __restrict__ cl,
                                              const float* __restrict__ w,
                                              _Float16* __restrict__ wg) {
  __shared__ _Float16 lt[32 * 68];
  int tid = threadIdx.x;
  int blk = blockIdx.x;
  if (blk >= 2304) {
    int i = (blk - 2304) * 256 + tid;        // 0..36863
    int o = i / 576;
    int r = i - o * 576;                     // tap*64 + c
    int t = r >> 6, c = r & 63;
    wg[((size_t)(t * 8 + (c >> 3)) * 64 + o) * 8 + (c & 7)] =
        (_Float16)w[(o * 64 + c) * 9 + t];
    return;
  }
  int xt = blk % 3;
  int rr = blk / 3;
  int y = rr % Hs;
  int b = rr / Hs;
  int x0 = xt * 32;
  {
    int xx = tid & 31, cc = tid >> 5;
    const float* src = in + (size_t)b * 64 * HW + y * Ws + x0 + xx;
#pragma unroll
    for (int i = 0; i < 8; ++i) {
      int c = cc * 8 + i;
      lt[xx * 68 + c] = (_Float16)src[(size_t)c * HW];
    }
  }
  __syncthreads();
  {
    int c4 = tid & 15, pg = tid >> 4;
    _Float16* dst = cl + ((size_t)(b * Hs + y) * Ws + x0) * 64 + c4 * 4;
#pragma unroll
    for (int i = 0; i < 2; ++i) {
      int x = pg * 2 + i;
      *(uint2*)(dst + (size_t)x * 64) = *(const uint2*)(lt + x * 68 + c4 * 4);
    }
  }
}

// ---- kernel 2: barrier-free fused sampling + implicit GEMM ----
// Block: 128 threads = 2 waves, 64 pixels. Grid: 1152 = 8 images (blk&7)
// x 144 tiles. Wave w owns pixels [w*32, w*32+32) as 2 MFMA pixel-groups and
// computes ALL 64 output channels for them (acc[2][4]). B-fragments are
// built DIRECTLY in registers: lane (q4,n16) gathers 16B of pixel n16's
// corner rows (quad lanes contiguous 64B -> 16 L1 lines/instr, same as the
// cooperative scheme) and interpolates in-register. 18 (tap,kc) stages,
// fully unrolled, depth-1 register double-buffer; NO __syncthreads in the
// K-loop -> no phase serialization.
__global__ __launch_bounds__(128, 3) void k_fused(
    const _Float16* __restrict__ incl, const float* __restrict__ off,
    const float* __restrict__ msk, const _Float16* __restrict__ wg,
    const float* __restrict__ bias, float* __restrict__ out) {
  __shared__ unsigned preA[576];     // 2,304 B
  __shared__ uint4 preW[576];        // 9,216 B (4 pre-duplicated h2 weights)

  int tid = threadIdx.x;
  int blk = blockIdx.x;
  int b = blk & 7;              // XCD swizzle: image b on XCD b
  int q0 = (blk >> 3) * 64;     // 144 pixel-tiles per image

  // phase pre: per-(pixel,tap) packed corner address + duplicated weights
  for (int i = tid; i < 576; i += 128) {
    int t = i >> 6, p = i & 63;
    int q = q0 + p;
    int qy = (int)(((unsigned)q * 43691u) >> 22);   // q/96 for q<9216
    int qx = q - qy * 96;
    int ty = t / 3, tx = t - ty * 3;
    float dy = off[(size_t)(b * 18 + 2 * t) * HW + q];
    float dx = off[(size_t)(b * 18 + 2 * t + 1) * HW + q];
    float mv = msk[(size_t)(b * 9 + t) * HW + q];
    float yf = (float)(qy - 1 + ty) + dy;
    float xf = (float)(qx - 1 + tx) + dx;
    float y0f = floorf(yf), x0f = floorf(xf);
    float wy = yf - y0f, wx = xf - x0f;
    int y0 = (int)y0f, x0i = (int)x0f;
    int y1 = y0 + 1, x1 = x0i + 1;
    bool yv0 = (y0 >= 0) && (y0 < Hs);
    bool yv1 = (y1 >= 0) && (y1 < Hs);
    bool xv0 = (x0i >= 0) && (x0i < Ws);
    bool xv1 = (x1 >= 0) && (x1 < Ws);
    int y0c = min(max(y0, 0), Hs - 1), y1c = min(max(y1, 0), Hs - 1);
    int x0c = min(max(x0i, 0), Ws - 1), x1c = min(max(x1, 0), Ws - 1);
    float omy = 1.f - wy, omx = 1.f - wx;
    float f00 = omy * omx * mv * ((yv0 && xv0) ? 1.f : 0.f);
    float f01 = omy * wx  * mv * ((yv0 && xv1) ? 1.f : 0.f);
    float f10 = wy  * omx * mv * ((yv1 && xv0) ? 1.f : 0.f);
    float f11 = wy  * wx  * mv * ((yv1 && xv1) ? 1.f : 0.f);
    preA[i] = ((unsigned)(b * HW + y0c * 96 + x0c) * 128u) |
              (unsigned)(x1c - x0c) | ((unsigned)(y1c - y0c) << 1);
    uint4 pw;
    pw.x = __builtin_bit_cast(unsigned, __builtin_amdgcn_cvt_pkrtz(f00, f00));
    pw.y = __builtin_bit_cast(unsigned, __builtin_amdgcn_cvt_pkrtz(f01, f01));
    pw.z = __builtin_bit_cast(unsigned, __builtin_amdgcn_cvt_pkrtz(f10, f10));
    pw.w = __builtin_bit_cast(unsigned, __builtin_amdgcn_cvt_pkrtz(f11, f11));
    preW[i] = pw;
  }
  __syncthreads();

  int lane = tid & 63, w = tid >> 6;     // w 0..1
  int n16 = lane & 15, q4 = lane >> 4;
  const char* inb = (const char*)incl;
  const uint4* Ag = (const uint4*)wg;    // plane p: Ag[p*64 + m]
  int pp0 = (w * 2) * 16 + n16;          // pixel of pg 0
  int pp1 = (w * 2 + 1) * 16 + n16;      // pixel of pg 1

  f32x4 acc[2][4];
#pragma unroll
  for (int pgi = 0; pgi < 2; ++pgi)
#pragma unroll
    for (int mt = 0; mt < 4; ++mt) {
      f32x4 z = {0.f, 0.f, 0.f, 0.f};
      acc[pgi][mt] = z;
    }

  uint4 af[2][4];        // A-fragments, double-buffered per stage
  uint4 ga[2][2][4];     // gathers: [buf][pg][corner]

#define LOADK(T, KC, BB)                                                      \
  {                                                                           \
    _Pragma("unroll") for (int mt = 0; mt < 4; ++mt)                          \
        af[BB][mt] =                                                          \
            Ag[(size_t)(((T) * 8 + (KC) * 4 + q4) * 64 + mt * 16 + n16)];     \
    _Pragma("unroll") for (int pgi = 0; pgi < 2; ++pgi) {                     \
      int p_ = pgi ? pp1 : pp0;                                               \
      unsigned ax = preA[(T) * 64 + p_];                                      \
      int a00 = (int)(ax & ~127u) + (KC) * 64 + q4 * 16;                      \
      int a01 = a00 + ((ax & 1) << 7);                                        \
      int a10 = a00 + ((ax & 2) * 6144);                                      \
      int a11 = a10 + ((ax & 1) << 7);                                        \
      ga[BB][pgi][0] = *(const uint4*)(inb + a00);                            \
      ga[BB][pgi][1] = *(const uint4*)(inb + a01);                            \
      ga[BB][pgi][2] = *(const uint4*)(inb + a10);                            \
      ga[BB][pgi][3] = *(const uint4*)(inb + a11);                            \
    }                                                                         \
  }

  LOADK(0, 0, 0)

#pragma unroll
  for (int s = 0; s < 18; ++s) {
    const int buf = s & 1;
    if (s < 17) {
      const int sn = s + 1;
      LOADK(sn >> 1, sn & 1, buf ^ 1)
    }
    const int t = s >> 1;
#pragma unroll
    for (int pgi = 0; pgi < 2; ++pgi) {
      uint4 pw = preW[t * 64 + (pgi ? pp1 : pp0)];
      h2 w00 = __builtin_bit_cast(h2, pw.x);
      h2 w01 = __builtin_bit_cast(h2, pw.y);
      h2 w10 = __builtin_bit_cast(h2, pw.z);
      h2 w11 = __builtin_bit_cast(h2, pw.w);
      uint4 bfu;
      bfu.x = interp4(w00, w01, w10, w11, ga[buf][pgi][0].x, ga[buf][pgi][1].x,
                      ga[buf][pgi][2].x, ga[buf][pgi][3].x);
      bfu.y = interp4(w00, w01, w10, w11, ga[buf][pgi][0].y, ga[buf][pgi][1].y,
                      ga[buf][pgi][2].y, ga[buf][pgi][3].y);
      bfu.z = interp4(w00, w01, w10, w11, ga[buf][pgi][0].z, ga[buf][pgi][1].z,
                      ga[buf][pgi][2].z, ga[buf][pgi][3].z);
      bfu.w = interp4(w00, w01, w10, w11, ga[buf][pgi][0].w, ga[buf][pgi][1].w,
                      ga[buf][pgi][2].w, ga[buf][pgi][3].w);
      f16x8 bf = __builtin_bit_cast(f16x8, bfu);
#pragma unroll
      for (int mt = 0; mt < 4; ++mt)
        acc[pgi][mt] = __builtin_amdgcn_mfma_f32_16x16x32_f16(
            __builtin_bit_cast(f16x8, af[buf][mt]), bf, acc[pgi][mt], 0, 0, 0);
    }
  }
#undef LOADK

  // epilogue: D col = pixel (n16), row m = mt*16 + q4*4 + r
#pragma unroll
  for (int pgi = 0; pgi < 2; ++pgi) {
    int col = q0 + (w * 2 + pgi) * 16 + n16;
    float* op = out + (size_t)b * 64 * HW + col;
#pragma unroll
    for (int mt = 0; mt < 4; ++mt) {
#pragma unroll
      for (int r = 0; r < 4; ++r) {
        int m = mt * 16 + q4 * 4 + r;
        op[(size_t)m * HW] = acc[pgi][mt][r] + bias[m];
      }
    }
  }
}

extern "C" void kernel_launch(void* const* d_in, const int* in_sizes, int n_in,
                              void* d_out, int out_size, void* d_ws, size_t ws_size,
                              hipStream_t stream) {
  const float* input = (const float*)d_in[0];
  const float* offset = (const float*)d_in[1];
  const float* mask = (const float*)d_in[2];
  const float* weight = (const float*)d_in[3];
  const float* bias = (const float*)d_in[4];
  float* out = (float*)d_out;

  _Float16* incl = (_Float16*)d_ws;                              // 9,437,184 B
  _Float16* wg = (_Float16*)((char*)d_ws + 9437184);             // 73,728 B

  k_prep<<<dim3(2448), dim3(256), 0, stream>>>(input, incl, weight, wg);
  k_fused<<<dim3(1152), dim3(128), 0, stream>>>(incl, offset, mask, wg, bias, out);
}

// Round 11
// 100.266 us; speedup vs baseline: 1.2919x; 1.2919x over previous
//
#include <hip/hip_runtime.h>
#include <stdint.h>

#define Hs 96
#define Ws 96
#define HW 9216

typedef _Float16 h2 __attribute__((ext_vector_type(2)));
typedef _Float16 f16x8 __attribute__((ext_vector_type(8)));
typedef float f32x4 __attribute__((ext_vector_type(4)));

// nested-fma bilinear: 1 pk_mul + 3 pk_fma (FP contraction)
__device__ __forceinline__ unsigned interp4(h2 w00, h2 w01, h2 w10, h2 w11,
                                            unsigned a, unsigned bq, unsigned c,
                                            unsigned d) {
  h2 r = w10 * __builtin_bit_cast(h2, c) + w11 * __builtin_bit_cast(h2, d);
  r = w01 * __builtin_bit_cast(h2, bq) + r;
  r = w00 * __builtin_bit_cast(h2, a) + r;
  return __builtin_bit_cast(unsigned, r);
}

// ---- kernel 1: fused prep ----
// blk < 2304: NCHW fp32 -> NHWC fp16 transpose (32x-tile per block)
// blk >= 2304: weight fp32 [O][C][9] -> fp16 planes Wg[t*8+c8][o][8ch]
__global__ __launch_bounds__(256) void k_prep(const float* __restrict__ in,
                                              _Float16* __restrict__ cl,
                                              const float* __restrict__ w,
                                              _Float16* __restrict__ wg) {
  __shared__ _Float16 lt[32 * 68];
  int tid = threadIdx.x;
  int blk = blockIdx.x;
  if (blk >= 2304) {
    int i = (blk - 2304) * 256 + tid;        // 0..36863
    int o = i / 576;
    int r = i - o * 576;                     // tap*64 + c
    int t = r >> 6, c = r & 63;
    wg[((size_t)(t * 8 + (c >> 3)) * 64 + o) * 8 + (c & 7)] =
        (_Float16)w[(o * 64 + c) * 9 + t];
    return;
  }
  int xt = blk % 3;
  int rr = blk / 3;
  int y = rr % Hs;
  int b = rr / Hs;
  int x0 = xt * 32;
  {
    int xx = tid & 31, cc = tid >> 5;
    const float* src = in + (size_t)b * 64 * HW + y * Ws + x0 + xx;
#pragma unroll
    for (int i = 0; i < 8; ++i) {
      int c = cc * 8 + i;
      lt[xx * 68 + c] = (_Float16)src[(size_t)c * HW];
    }
  }
  __syncthreads();
  {
    int c4 = tid & 15, pg = tid >> 4;
    _Float16* dst = cl + ((size_t)(b * Hs + y) * Ws + x0) * 64 + c4 * 4;
#pragma unroll
    for (int i = 0; i < 2; ++i) {
      int x = pg * 2 + i;
      *(uint2*)(dst + (size_t)x * 64) = *(const uint2*)(lt + x * 68 + c4 * 4);
    }
  }
}

// ---- kernel 2: fused sampling + implicit GEMM, drain-free tap pipeline ----
// Block: 256 threads, 64 pixels. Grid: 1152 = 8 images (blk&7) x 144 tiles.
// All 1152 blocks resident at 5 blocks/CU -> zero tail.
// Sampling: 8-lane group <-> pixel, lane j <-> 16B channel chunk.
// GEMM: wave wv owns output channels [wv*16, wv*16+16).
// NOTE (R3/R10 lesson): register-level prefetch of scattered gathers gets
// collapsed by the compiler; this LDS-buffered barrier pipeline is the form
// that survives codegen (gathers forced live by the LDS store).
__global__ __launch_bounds__(256, 5) void k_fused(
    const _Float16* __restrict__ incl, const float* __restrict__ off,
    const float* __restrict__ msk, const _Float16* __restrict__ wg,
    const float* __restrict__ bias, float* __restrict__ out) {
  __shared__ unsigned preA[576];     // 2,304 B
  __shared__ uint4 preW[576];        // 9,216 B (4 pre-duplicated h2 weights)
  __shared__ uint4 Vb[2][64 * 9];    // 18,432 B (9 uint4 = 144 B per pixel)

  int tid = threadIdx.x;
  int blk = blockIdx.x;
  int b = blk & 7;              // XCD swizzle: image b on XCD b
  int q0 = (blk >> 3) * 64;     // 144 pixel-tiles per image

  // phase pre: per-(pixel,tap) packed corner address + duplicated weights
  for (int i = tid; i < 576; i += 256) {
    int t = i >> 6, p = i & 63;
    int q = q0 + p;
    int qy = (int)(((unsigned)q * 43691u) >> 22);   // q/96 for q<9216
    int qx = q - qy * 96;
    int ty = t / 3, tx = t - ty * 3;
    float dy = off[(size_t)(b * 18 + 2 * t) * HW + q];
    float dx = off[(size_t)(b * 18 + 2 * t + 1) * HW + q];
    float mv = msk[(size_t)(b * 9 + t) * HW + q];
    float yf = (float)(qy - 1 + ty) + dy;
    float xf = (float)(qx - 1 + tx) + dx;
    float y0f = floorf(yf), x0f = floorf(xf);
    float wy = yf - y0f, wx = xf - x0f;
    int y0 = (int)y0f, x0i = (int)x0f;
    int y1 = y0 + 1, x1 = x0i + 1;
    bool yv0 = (y0 >= 0) && (y0 < Hs);
    bool yv1 = (y1 >= 0) && (y1 < Hs);
    bool xv0 = (x0i >= 0) && (x0i < Ws);
    bool xv1 = (x1 >= 0) && (x1 < Ws);
    int y0c = min(max(y0, 0), Hs - 1), y1c = min(max(y1, 0), Hs - 1);
    int x0c = min(max(x0i, 0), Ws - 1), x1c = min(max(x1, 0), Ws - 1);
    float omy = 1.f - wy, omx = 1.f - wx;
    float f00 = omy * omx * mv * ((yv0 && xv0) ? 1.f : 0.f);
    float f01 = omy * wx  * mv * ((yv0 && xv1) ? 1.f : 0.f);
    float f10 = wy  * omx * mv * ((yv1 && xv0) ? 1.f : 0.f);
    float f11 = wy  * wx  * mv * ((yv1 && xv1) ? 1.f : 0.f);
    preA[i] = ((unsigned)(b * HW + y0c * 96 + x0c) * 128u) |
              (unsigned)(x1c - x0c) | ((unsigned)(y1c - y0c) << 1);
    uint4 pw;
    pw.x = __builtin_bit_cast(unsigned, __builtin_amdgcn_cvt_pkrtz(f00, f00));
    pw.y = __builtin_bit_cast(unsigned, __builtin_amdgcn_cvt_pkrtz(f01, f01));
    pw.z = __builtin_bit_cast(unsigned, __builtin_amdgcn_cvt_pkrtz(f10, f10));
    pw.w = __builtin_bit_cast(unsigned, __builtin_amdgcn_cvt_pkrtz(f11, f11));
    preW[i] = pw;
  }
  __syncthreads();

  int j = tid & 7;
  int g = tid >> 3;            // 0..31 (sampling group)
  int lane = tid & 63, wv = tid >> 6;
  int n16 = lane & 15, q4 = lane >> 4;
  const char* inb = (const char*)incl;
  const uint4* Ag = (const uint4*)wg;   // plane p: Ag[p*64 + m]
  int arow = wv * 16 + n16;             // A-operand m index for this lane

  f32x4 acc[4];
#pragma unroll
  for (int pg = 0; pg < 4; ++pg) {
    f32x4 z = {0.f, 0.f, 0.f, 0.f};
    acc[pg] = z;
  }

  uint4 ga[2][4];     // gathers for current tap: 2 pixel-subgroups x 4 corners
  uint4 afn0, afn1;   // prefetched A-fragments (next tap)

#define ISSUE_GATHERS(T)                                                     \
  _Pragma("unroll") for (int it = 0; it < 2; ++it) {                         \
    int gg = g + it * 32;                                                    \
    unsigned ax = preA[(T) * 64 + gg];                                       \
    int a00 = (int)(ax & ~127u) + j * 16;                                    \
    int a01 = a00 + ((ax & 1) << 7);                                         \
    int a10 = a00 + ((ax & 2) * 6144);                                       \
    int a11 = a10 + ((ax & 1) << 7);                                         \
    ga[it][0] = *(const uint4*)(inb + a00);                                  \
    ga[it][1] = *(const uint4*)(inb + a01);                                  \
    ga[it][2] = *(const uint4*)(inb + a10);                                  \
    ga[it][3] = *(const uint4*)(inb + a11);                                  \
  }

  // prologue: tap 0 gathers + tap 0 A-fragments
  ISSUE_GATHERS(0)
  afn0 = Ag[(size_t)((0 + q4) * 64 + arow)];
  afn1 = Ag[(size_t)((4 + q4) * 64 + arow)];

#pragma unroll
  for (int t = 0; t < 9; ++t) {
    int buf = t & 1;
    // interp tap t (consumes ga; hw waits its vmcnt here)
    uint4 v0, v1;
#pragma unroll
    for (int it = 0; it < 2; ++it) {
      int gg = g + it * 32;
      uint4 pw = preW[t * 64 + gg];
      h2 w00 = __builtin_bit_cast(h2, pw.x);
      h2 w01 = __builtin_bit_cast(h2, pw.y);
      h2 w10 = __builtin_bit_cast(h2, pw.z);
      h2 w11 = __builtin_bit_cast(h2, pw.w);
      uint4 r;
      r.x = interp4(w00, w01, w10, w11, ga[it][0].x, ga[it][1].x, ga[it][2].x, ga[it][3].x);
      r.y = interp4(w00, w01, w10, w11, ga[it][0].y, ga[it][1].y, ga[it][2].y, ga[it][3].y);
      r.z = interp4(w00, w01, w10, w11, ga[it][0].z, ga[it][1].z, ga[it][2].z, ga[it][3].z);
      r.w = interp4(w00, w01, w10, w11, ga[it][0].w, ga[it][1].w, ga[it][2].w, ga[it][3].w);
      if (it == 0) v0 = r; else v1 = r;
    }
    uint4 afc0 = afn0, afc1 = afn1;
    Vb[buf][g * 9 + j] = v0;
    Vb[buf][(g + 32) * 9 + j] = v1;
    __syncthreads();   // vm queue ~empty here -> drain is cheap
    if (t < 8) {
      // issue next tap's loads; consumed before the NEXT barrier
      ISSUE_GATHERS(t + 1)
      afn0 = Ag[(size_t)(((t + 1) * 8 + q4) * 64 + arow)];
      afn1 = Ag[(size_t)(((t + 1) * 8 + 4 + q4) * 64 + arow)];
    }
    // MFMA on tap t: wave wv covers m in [wv*16, wv*16+16), all 64 pixels
#pragma unroll
    for (int pg = 0; pg < 4; ++pg) {
      f16x8 b0 = __builtin_bit_cast(f16x8, Vb[buf][(pg * 16 + n16) * 9 + q4]);
      f16x8 b1 = __builtin_bit_cast(f16x8, Vb[buf][(pg * 16 + n16) * 9 + 4 + q4]);
      acc[pg] = __builtin_amdgcn_mfma_f32_16x16x32_f16(
          __builtin_bit_cast(f16x8, afc0), b0, acc[pg], 0, 0, 0);
      acc[pg] = __builtin_amdgcn_mfma_f32_16x16x32_f16(
          __builtin_bit_cast(f16x8, afc1), b1, acc[pg], 0, 0, 0);
    }
  }
#undef ISSUE_GATHERS

  // epilogue: D col = pixel (n16), row m = wv*16 + q4*4 + r
  int m0 = wv * 16 + q4 * 4;
  float bv[4];
#pragma unroll
  for (int r = 0; r < 4; ++r) bv[r] = bias[m0 + r];
#pragma unroll
  for (int pg = 0; pg < 4; ++pg) {
    int col = q0 + pg * 16 + n16;
    float* op = out + (size_t)b * 64 * HW + col;
#pragma unroll
    for (int r = 0; r < 4; ++r)
      op[(size_t)(m0 + r) * HW] = acc[pg][r] + bv[r];
  }
}

extern "C" void kernel_launch(void* const* d_in, const int* in_sizes, int n_in,
                              void* d_out, int out_size, void* d_ws, size_t ws_size,
                              hipStream_t stream) {
  const float* input = (const float*)d_in[0];
  const float* offset = (const float*)d_in[1];
  const float* mask = (const float*)d_in[2];
  const float* weight = (const float*)d_in[3];
  const float* bias = (const float*)d_in[4];
  float* out = (float*)d_out;

  _Float16* incl = (_Float16*)d_ws;                              // 9,437,184 B
  _Float16* wg = (_Float16*)((char*)d_ws + 9437184);             // 73,728 B

  k_prep<<<dim3(2448), dim3(256), 0, stream>>>(input, incl, weight, wg);
  k_fused<<<dim3(1152), dim3(256), 0, stream>>>(incl, offset, mask, wg, bias, out);
}